// Round 6
// baseline (141.767 us; speedup 1.0000x reference)
//
#include <hip/hip_runtime.h>

// B=4, C=256, CR=64, H=W=64, K=7, KK=49, GROUPS=16, GC=16
#define BN_EPS 1e-5f

typedef __bf16 bf16_t;
typedef __bf16 bf16x8 __attribute__((ext_vector_type(8)));
typedef __bf16 bf16x4 __attribute__((ext_vector_type(4)));
typedef __bf16 bf16x2 __attribute__((ext_vector_type(2)));
typedef float  floatx4 __attribute__((ext_vector_type(4)));

#define MFMA16(a, b, c) __builtin_amdgcn_mfma_f32_16x16x32_bf16((a), (b), (c), 0, 0, 0)

// ws layout (total ~29.7 MB)
#define XT_OFF  0                       // 16384*64 bf16 = 2 MB
#define WG_OFF  0x200000                // 784*16384 bf16 = 25.69 MB
#define W1B_OFF 0x1A80000               // 64*256 bf16
#define W2B_OFF (0x1A80000 + 32768)     // 784*64 bf16
#define B1_OFF  (0x1A80000 + 32768 + 100352)

// ---------------------------------------------------------------------------
// K0 prep: fold BN into w1 (bf16), w2 -> bf16, bias1. 260 blocks.
// ---------------------------------------------------------------------------
__global__ __launch_bounds__(256) void prep(
    const float* __restrict__ w1, const float* __restrict__ gamma,
    const float* __restrict__ beta, const float* __restrict__ mean,
    const float* __restrict__ var, const float* __restrict__ w2,
    bf16_t* __restrict__ w1b, bf16_t* __restrict__ w2b, float* __restrict__ bias1)
{
    const int idx = blockIdx.x * 256 + threadIdx.x;
    if (idx < 16384) {
        const int o = idx >> 8;
        const float inv = gamma[o] * rsqrtf(var[o] + BN_EPS);
        w1b[idx] = (bf16_t)(w1[idx] * inv);
        if (idx < 64) {
            const float iv = gamma[idx] * rsqrtf(var[idx] + BN_EPS);
            bias1[idx] = beta[idx] - mean[idx] * iv;
        }
    } else if (idx < 16384 + 50176) {
        const int j = idx - 16384;
        w2b[j] = (bf16_t)w2[j];
    }
}

// ---------------------------------------------------------------------------
// K1 conv1: one block per (b,h). In-LDS transpose of guide row -> bf16 [p][c],
// then barrier-free MFMA: x[64o][64p] = w1b . gT; ReLU+bias; write xT[bp][o].
// 256 blocks (R2-validated structure, ~7 us).
// ---------------------------------------------------------------------------
#define GTP 264

__global__ __launch_bounds__(256) void conv1_k(
    const float* __restrict__ guide, const bf16_t* __restrict__ w1b,
    const float* __restrict__ bias1, bf16_t* __restrict__ xT)
{
    __shared__ __attribute__((aligned(16))) bf16_t gTs[64 * GTP];  // 33.8 KB
    const int b = blockIdx.x >> 6, h = blockIdx.x & 63;
    const int t = threadIdx.x;

    const float* gsrc = guide + (size_t)b * 256 * 4096 + h * 64;
#pragma unroll
    for (int i = 0; i < 32; ++i) {
        const int idx = i * 256 + t;
        const int c2 = idx >> 6, p = idx & 63;
        const float g0 = gsrc[(size_t)(2 * c2) * 4096 + p];
        const float g1 = gsrc[(size_t)(2 * c2 + 1) * 4096 + p];
        bf16x2 pk; pk[0] = (bf16_t)g0; pk[1] = (bf16_t)g1;
        *(bf16x2*)&gTs[p * GTP + 2 * c2] = pk;
    }
    __syncthreads();

    const int wv = t >> 6, ln = t & 63, l15 = ln & 15, q = ln >> 4;
    floatx4 acc[4] = {};
    const bf16_t* ap = w1b + (wv * 16 + l15) * 256;
#pragma unroll
    for (int ks = 0; ks < 8; ++ks) {
        const bf16x8 a = *(const bf16x8*)(ap + ks * 32 + q * 8);
#pragma unroll
        for (int nt = 0; nt < 4; ++nt) {
            const bf16x8 bb = *(const bf16x8*)&gTs[(nt * 16 + l15) * GTP + ks * 32 + q * 8];
            acc[nt] = MFMA16(a, bb, acc[nt]);
        }
    }
    float bi[4];
#pragma unroll
    for (int j = 0; j < 4; ++j) bi[j] = bias1[wv * 16 + q * 4 + j];
#pragma unroll
    for (int nt = 0; nt < 4; ++nt) {
        const int p = nt * 16 + l15;
        bf16x4 v;
#pragma unroll
        for (int j = 0; j < 4; ++j) v[j] = (bf16_t)fmaxf(acc[nt][j] + bi[j], 0.f);
        *(bf16x4*)(xT + ((size_t)(b * 64 + h) * 64 + p) * 64 + wv * 16 + q * 4) = v;
    }
}

// ---------------------------------------------------------------------------
// K2 conv2: one block = (ptile, g); blockIdx = ptile*16 + g (XCD = g%8).
// GEMM: wg[49k x 128p] = w2b[g] (49x64) . xT (64c x 128p), +b2, bf16.
// Direct-global A/B fragments (both c-contiguous, L1/L2-hot), no input LDS.
// Epilogue: LDS transpose -> coalesced uint4 stores of wg rows.
// 2048 blocks = 8/CU.
// ---------------------------------------------------------------------------
#define WTP 136

__global__ __launch_bounds__(256) void conv2_k(
    const bf16_t* __restrict__ xT, const bf16_t* __restrict__ w2b,
    const float* __restrict__ b2, bf16_t* __restrict__ wg)
{
    __shared__ __attribute__((aligned(16))) bf16_t wgt[64 * WTP];  // 17.4 KB
    const int g = blockIdx.x & 15;
    const int bp0 = (blockIdx.x >> 4) * 128;
    const int t = threadIdx.x;
    const int wv = t >> 6, ln = t & 63, l15 = ln & 15, q = ln >> 4;

    floatx4 acc[4][2] = {};
    const bf16_t* brow = xT + (size_t)(bp0 + wv * 32) * 64;
#pragma unroll
    for (int ks = 0; ks < 2; ++ks) {
        bf16x8 bfr[2];
        bfr[0] = *(const bf16x8*)(brow + l15 * 64 + ks * 32 + q * 8);
        bfr[1] = *(const bf16x8*)(brow + (16 + l15) * 64 + ks * 32 + q * 8);
#pragma unroll
        for (int mt = 0; mt < 4; ++mt) {
            int row = mt * 16 + l15; if (row > 48) row = 48;   // clamped pad rows, never stored
            const bf16x8 a = *(const bf16x8*)(w2b + (size_t)(g * 49 + row) * 64 + ks * 32 + q * 8);
            acc[mt][0] = MFMA16(a, bfr[0], acc[mt][0]);
            acc[mt][1] = MFMA16(a, bfr[1], acc[mt][1]);
        }
    }
#pragma unroll
    for (int mt = 0; mt < 4; ++mt) {
#pragma unroll
        for (int j = 0; j < 4; ++j) {
            const int k = mt * 16 + q * 4 + j;
            if (k < 49) {
                const float bias = b2[g * 49 + k];
                wgt[k * WTP + wv * 32 + l15]      = (bf16_t)(acc[mt][0][j] + bias);
                wgt[k * WTP + wv * 32 + 16 + l15] = (bf16_t)(acc[mt][1][j] + bias);
            }
        }
    }
    __syncthreads();
    // copy out 49 rows x 128 px as uint4: rows contiguous in wg -> coalesced
    for (int u = t; u < 784; u += 256) {
        const int k = u >> 4, c16 = u & 15;
        *(uint4*)(wg + (size_t)(g * 49 + k) * 16384 + bp0 + c16 * 8) =
            *(const uint4*)&wgt[k * WTP + c16 * 8];
    }
}

// ---------------------------------------------------------------------------
// K3 agg: one block = (g, b, h-quad); blockIdx = ((b*16+hq)*16) + g (XCD = g%8,
// matches K2's producer). Stage wg tile [49k][256px] LDS (uint4 coalesced),
// then fp32 aggregation: thread = (4 w, 1 row, 4 ch) -> 16 outputs + residual.
// 1024 blocks.
// ---------------------------------------------------------------------------
#define WGLP 264

__global__ __launch_bounds__(256) void agg_k(
    const bf16_t* __restrict__ wg, const float* __restrict__ feat,
    float* __restrict__ out)
{
    __shared__ __attribute__((aligned(16))) bf16_t wgl[49 * WGLP];  // 25.3 KB
    const int g = blockIdx.x & 15;
    const int rest = blockIdx.x >> 4;      // 0..63
    const int b = rest >> 4, hq = rest & 15;
    const int t = threadIdx.x;

    // stage 49 x 256 px (this g, this h-quad)
#pragma unroll
    for (int i = 0; i < 7; ++i) {
        const int u = i * 256 + t;
        if (u < 1568) {
            const int k = u >> 5, off = (u & 31) * 8;
            *(uint4*)&wgl[k * WGLP + off] =
                *(const uint4*)(wg + (size_t)(g * 49 + k) * 16384 + b * 4096 + hq * 256 + off);
        }
    }
    __syncthreads();

    const int wq = t & 15, r = (t >> 4) & 3, cp = t >> 6;
    const int w0 = wq * 4;
    const int ch0 = g * 16 + cp * 4;
    const int hr = hq * 4 + r;

    float acc[4][4] = {};
    float4 res[4];
#pragma unroll
    for (int di = 0; di < 7; ++di) {
        const int hh = hr + di - 3;
        if (hh < 0 || hh >= 64) continue;   // di==3 always in range
        float f[4][10];
#pragma unroll
        for (int c = 0; c < 4; ++c) {
            const float* rp = feat + ((size_t)(b * 256 + ch0 + c) * 64 + hh) * 64;
            float4 L = {0, 0, 0, 0}, R = {0, 0, 0, 0};
            if (wq > 0)  L = *(const float4*)(rp + w0 - 4);
            const float4 M = *(const float4*)(rp + w0);
            if (wq < 15) R = *(const float4*)(rp + w0 + 4);
            if (di == 3) res[c] = M;
            f[c][0] = L.y; f[c][1] = L.z; f[c][2] = L.w; f[c][3] = M.x; f[c][4] = M.y;
            f[c][5] = M.z; f[c][6] = M.w; f[c][7] = R.x; f[c][8] = R.y; f[c][9] = R.z;
        }
        const bf16_t* wrow = &wgl[(di * 7) * WGLP + r * 64 + w0];
#pragma unroll
        for (int dj = 0; dj < 7; ++dj) {
            const bf16x4 wb = *(const bf16x4*)(wrow + dj * WGLP);
#pragma unroll
            for (int x = 0; x < 4; ++x) {
                const float wf = (float)wb[x];
#pragma unroll
                for (int c = 0; c < 4; ++c)
                    acc[c][x] = fmaf(wf, f[c][x + dj], acc[c][x]);
            }
        }
    }
#pragma unroll
    for (int c = 0; c < 4; ++c) {
        const size_t ob = ((size_t)(b * 256 + ch0 + c) * 64 + hr) * 64 + w0;
        float4 o;
        o.x = acc[c][0] + res[c].x; o.y = acc[c][1] + res[c].y;
        o.z = acc[c][2] + res[c].z; o.w = acc[c][3] + res[c].w;
        *(float4*)(out + ob) = o;
    }
}

extern "C" void kernel_launch(void* const* d_in, const int* in_sizes, int n_in,
                              void* d_out, int out_size, void* d_ws, size_t ws_size,
                              hipStream_t stream) {
    const float* feature = (const float*)d_in[0];
    const float* guide   = (const float*)d_in[1];
    const float* w1      = (const float*)d_in[2];
    const float* gamma   = (const float*)d_in[3];
    const float* beta    = (const float*)d_in[4];
    const float* mean    = (const float*)d_in[5];
    const float* var     = (const float*)d_in[6];
    const float* w2      = (const float*)d_in[7];
    const float* b2      = (const float*)d_in[8];
    float* out = (float*)d_out;

    char* ws = (char*)d_ws;
    bf16_t* xT    = (bf16_t*)(ws + XT_OFF);
    bf16_t* wg    = (bf16_t*)(ws + WG_OFF);
    bf16_t* w1b   = (bf16_t*)(ws + W1B_OFF);
    bf16_t* w2b   = (bf16_t*)(ws + W2B_OFF);
    float*  bias1 = (float*) (ws + B1_OFF);

    prep<<<260, 256, 0, stream>>>(w1, gamma, beta, mean, var, w2, w1b, w2b, bias1);
    conv1_k<<<256, 256, 0, stream>>>(guide, w1b, bias1, xT);
    conv2_k<<<2048, 256, 0, stream>>>(xT, w2b, b2, wg);
    agg_k<<<1024, 256, 0, stream>>>(wg, feature, out);
}

// Round 7
// 132.134 us; speedup vs baseline: 1.0729x; 1.0729x over previous
//
#include <hip/hip_runtime.h>

// B=4, C=256, CR=64, H=W=64, K=7, KK=49, GROUPS=16, GC=16
#define BN_EPS 1e-5f

typedef __bf16 bf16_t;
typedef __bf16 bf16x8 __attribute__((ext_vector_type(8)));
typedef __bf16 bf16x4 __attribute__((ext_vector_type(4)));
typedef __bf16 bf16x2 __attribute__((ext_vector_type(2)));
typedef float  floatx4 __attribute__((ext_vector_type(4)));

#define MFMA16(a, b, c) __builtin_amdgcn_mfma_f32_16x16x32_bf16((a), (b), (c), 0, 0, 0)

// ws layout (total ~29.7 MB)
#define XT_OFF  0                       // 16384*64 bf16 = 2 MB
#define WG_OFF  0x200000                // 784*16384 bf16 = 25.69 MB
#define W1B_OFF 0x1A80000               // 64*256 bf16
#define W2B_OFF (0x1A80000 + 32768)     // 784*64 bf16
#define B1_OFF  (0x1A80000 + 32768 + 100352)

// ---------------------------------------------------------------------------
// K0 prep: fold BN into w1 (bf16), w2 -> bf16, bias1. 260 blocks.
// ---------------------------------------------------------------------------
__global__ __launch_bounds__(256) void prep(
    const float* __restrict__ w1, const float* __restrict__ gamma,
    const float* __restrict__ beta, const float* __restrict__ mean,
    const float* __restrict__ var, const float* __restrict__ w2,
    bf16_t* __restrict__ w1b, bf16_t* __restrict__ w2b, float* __restrict__ bias1)
{
    const int idx = blockIdx.x * 256 + threadIdx.x;
    if (idx < 16384) {
        const int o = idx >> 8;
        const float inv = gamma[o] * rsqrtf(var[o] + BN_EPS);
        w1b[idx] = (bf16_t)(w1[idx] * inv);
        if (idx < 64) {
            const float iv = gamma[idx] * rsqrtf(var[idx] + BN_EPS);
            bias1[idx] = beta[idx] - mean[idx] * iv;
        }
    } else if (idx < 16384 + 50176) {
        const int j = idx - 16384;
        w2b[j] = (bf16_t)w2[j];
    }
}

// ---------------------------------------------------------------------------
// K1 conv1: one block per (b,h). In-LDS transpose of guide row -> bf16 [p][c],
// then barrier-free MFMA: x[64o][64p] = w1b . gT; ReLU+bias; write xT[bp][o].
// ---------------------------------------------------------------------------
#define GTP 264

__global__ __launch_bounds__(256) void conv1_k(
    const float* __restrict__ guide, const bf16_t* __restrict__ w1b,
    const float* __restrict__ bias1, bf16_t* __restrict__ xT)
{
    __shared__ __attribute__((aligned(16))) bf16_t gTs[64 * GTP];  // 33.8 KB
    const int b = blockIdx.x >> 6, h = blockIdx.x & 63;
    const int t = threadIdx.x;

    const float* gsrc = guide + (size_t)b * 256 * 4096 + h * 64;
#pragma unroll
    for (int i = 0; i < 32; ++i) {
        const int idx = i * 256 + t;
        const int c2 = idx >> 6, p = idx & 63;
        const float g0 = gsrc[(size_t)(2 * c2) * 4096 + p];
        const float g1 = gsrc[(size_t)(2 * c2 + 1) * 4096 + p];
        bf16x2 pk; pk[0] = (bf16_t)g0; pk[1] = (bf16_t)g1;
        *(bf16x2*)&gTs[p * GTP + 2 * c2] = pk;
    }
    __syncthreads();

    const int wv = t >> 6, ln = t & 63, l15 = ln & 15, q = ln >> 4;
    floatx4 acc[4] = {};
    const bf16_t* ap = w1b + (wv * 16 + l15) * 256;
#pragma unroll
    for (int ks = 0; ks < 8; ++ks) {
        const bf16x8 a = *(const bf16x8*)(ap + ks * 32 + q * 8);
#pragma unroll
        for (int nt = 0; nt < 4; ++nt) {
            const bf16x8 bb = *(const bf16x8*)&gTs[(nt * 16 + l15) * GTP + ks * 32 + q * 8];
            acc[nt] = MFMA16(a, bb, acc[nt]);
        }
    }
    float bi[4];
#pragma unroll
    for (int j = 0; j < 4; ++j) bi[j] = bias1[wv * 16 + q * 4 + j];
#pragma unroll
    for (int nt = 0; nt < 4; ++nt) {
        const int p = nt * 16 + l15;
        bf16x4 v;
#pragma unroll
        for (int j = 0; j < 4; ++j) v[j] = (bf16_t)fmaxf(acc[nt][j] + bi[j], 0.f);
        *(bf16x4*)(xT + ((size_t)(b * 64 + h) * 64 + p) * 64 + wv * 16 + q * 4) = v;
    }
}

// ---------------------------------------------------------------------------
// K2 conv2: one block = (ptile, g); blockIdx = ptile*16 + g (XCD = g%8).
// GEMM: wg[49k x 128p] = w2b[g] (49x64) . xT (64c x 128p), +b2, bf16.
// ---------------------------------------------------------------------------
#define WTP 136

__global__ __launch_bounds__(256) void conv2_k(
    const bf16_t* __restrict__ xT, const bf16_t* __restrict__ w2b,
    const float* __restrict__ b2, bf16_t* __restrict__ wg)
{
    __shared__ __attribute__((aligned(16))) bf16_t wgt[64 * WTP];  // 17.4 KB
    const int g = blockIdx.x & 15;
    const int bp0 = (blockIdx.x >> 4) * 128;
    const int t = threadIdx.x;
    const int wv = t >> 6, ln = t & 63, l15 = ln & 15, q = ln >> 4;

    floatx4 acc[4][2] = {};
    const bf16_t* brow = xT + (size_t)(bp0 + wv * 32) * 64;
#pragma unroll
    for (int ks = 0; ks < 2; ++ks) {
        bf16x8 bfr[2];
        bfr[0] = *(const bf16x8*)(brow + l15 * 64 + ks * 32 + q * 8);
        bfr[1] = *(const bf16x8*)(brow + (16 + l15) * 64 + ks * 32 + q * 8);
#pragma unroll
        for (int mt = 0; mt < 4; ++mt) {
            int row = mt * 16 + l15; if (row > 48) row = 48;   // clamped pad rows, never stored
            const bf16x8 a = *(const bf16x8*)(w2b + (size_t)(g * 49 + row) * 64 + ks * 32 + q * 8);
            acc[mt][0] = MFMA16(a, bfr[0], acc[mt][0]);
            acc[mt][1] = MFMA16(a, bfr[1], acc[mt][1]);
        }
    }
#pragma unroll
    for (int mt = 0; mt < 4; ++mt) {
#pragma unroll
        for (int j = 0; j < 4; ++j) {
            const int k = mt * 16 + q * 4 + j;
            if (k < 49) {
                const float bias = b2[g * 49 + k];
                wgt[k * WTP + wv * 32 + l15]      = (bf16_t)(acc[mt][0][j] + bias);
                wgt[k * WTP + wv * 32 + 16 + l15] = (bf16_t)(acc[mt][1][j] + bias);
            }
        }
    }
    __syncthreads();
    for (int u = t; u < 784; u += 256) {
        const int k = u >> 4, c16 = u & 15;
        *(uint4*)(wg + (size_t)(g * 49 + k) * 16384 + bp0 + c16 * 8) =
            *(const uint4*)&wgt[k * WTP + c16 * 8];
    }
}

// ---------------------------------------------------------------------------
// K3 agg v2: one block = (g, b, h-PAIR); blockIdx = ((b*32+hp)*16) + g
// (XCD = g%8, matches K2's producer).
//  Stage A (coalesced, ~13 uint4/thread):
//    fs[16 ch][8 rows][72 w] fp32, zero-padded (rows out of range and w pads)
//    wgl[49 k][136] bf16 (128 px = h-pair)
//  Compute (all LDS, branchless di loop): thread = (wq, r, cp) ->
//    2 ch x 4 w outputs; 392 FMA; residual from fs (exact fp32).
// LDS = 36 KB + 13.0 KB = 49.3 KB -> 3 blocks/CU. Grid 2048.
// ---------------------------------------------------------------------------
#define FSR 72     // fs row pitch (floats): [4 pad][64 w][4 pad]
#define FSC 576    // fs channel pitch = 8*72
#define WGLP 136   // wgl row pitch (bf16)

__global__ __launch_bounds__(256) void agg_k(
    const bf16_t* __restrict__ wg, const float* __restrict__ feat,
    float* __restrict__ out)
{
    __shared__ __attribute__((aligned(16))) float  fs[16 * FSC];     // 36.0 KB
    __shared__ __attribute__((aligned(16))) bf16_t wgl[49 * WGLP];   // 13.0 KB

    const int g = blockIdx.x & 15;
    const int rest = blockIdx.x >> 4;      // 0..127
    const int b = rest >> 5, hp = rest & 31;
    const int h0 = hp * 2;
    const int t = threadIdx.x;

    // ---- stage wgl: 49 x 128 px bf16 (784 uint4) ----
    for (int u = t; u < 784; u += 256) {
        const int k = u >> 4, c16 = u & 15;
        *(uint4*)&wgl[k * WGLP + c16 * 8] =
            *(const uint4*)(wg + (size_t)(g * 49 + k) * 16384 + b * 4096 + hp * 128 + c16 * 8);
    }
    // ---- stage fs: 16 ch x 8 rows x 18 quads (2304 uint4), zero-padded ----
#pragma unroll
    for (int i = 0; i < 9; ++i) {
        const int u = i * 256 + t;
        const int c = u / 144, rem = u - c * 144;
        const int rr = rem / 18, qq = rem - rr * 18;
        const int hh = h0 - 3 + rr;
        float4 v = {0.f, 0.f, 0.f, 0.f};
        if (qq >= 1 && qq <= 16 && hh >= 0 && hh < 64)
            v = *(const float4*)(feat + ((size_t)(b * 256 + g * 16 + c) * 64 + hh) * 64 + (qq - 1) * 4);
        *(float4*)&fs[c * FSC + rr * FSR + qq * 4] = v;
    }
    __syncthreads();

    // ---- compute: thread = (wq, r, cp) ----
    const int wq = t & 15, r = (t >> 4) & 1, cp = t >> 5;   // cp in [0,8)
    const int w0 = wq * 4;
    const int ch0 = cp * 2;

    float acc[2][4] = {};
#pragma unroll
    for (int di = 0; di < 7; ++di) {
        const int ri = r + di;             // 0..7, always valid (zero-padded rows)
        float f0[12], f1[12];
        {
            const float* p0 = &fs[ch0 * FSC + ri * FSR + w0];
            const float* p1 = p0 + FSC;
#pragma unroll
            for (int qj = 0; qj < 3; ++qj) {
                const floatx4 a = *(const floatx4*)(p0 + qj * 4);
                const floatx4 bq = *(const floatx4*)(p1 + qj * 4);
#pragma unroll
                for (int j = 0; j < 4; ++j) { f0[qj * 4 + j] = a[j]; f1[qj * 4 + j] = bq[j]; }
            }
        }
        const bf16_t* wrow = &wgl[(di * 7) * WGLP + r * 64 + w0];
#pragma unroll
        for (int dj = 0; dj < 7; ++dj) {
            const bf16x4 wb = *(const bf16x4*)(wrow + dj * WGLP);
#pragma unroll
            for (int x = 0; x < 4; ++x) {
                const float wf = (float)wb[x];
                acc[0][x] = fmaf(wf, f0[x + dj + 1], acc[0][x]);
                acc[1][x] = fmaf(wf, f1[x + dj + 1], acc[1][x]);
            }
        }
    }

    // residual from staged fp32 tile (row r+3 is h0+r, exact), + store
#pragma unroll
    for (int c = 0; c < 2; ++c) {
        const floatx4 res = *(const floatx4*)&fs[(ch0 + c) * FSC + (r + 3) * FSR + 4 + w0];
        const size_t ob = ((size_t)(b * 256 + g * 16 + ch0 + c) * 64 + h0 + r) * 64 + w0;
        float4 o;
        o.x = acc[c][0] + res[0]; o.y = acc[c][1] + res[1];
        o.z = acc[c][2] + res[2]; o.w = acc[c][3] + res[3];
        *(float4*)(out + ob) = o;
    }
}

extern "C" void kernel_launch(void* const* d_in, const int* in_sizes, int n_in,
                              void* d_out, int out_size, void* d_ws, size_t ws_size,
                              hipStream_t stream) {
    const float* feature = (const float*)d_in[0];
    const float* guide   = (const float*)d_in[1];
    const float* w1      = (const float*)d_in[2];
    const float* gamma   = (const float*)d_in[3];
    const float* beta    = (const float*)d_in[4];
    const float* mean    = (const float*)d_in[5];
    const float* var     = (const float*)d_in[6];
    const float* w2      = (const float*)d_in[7];
    const float* b2      = (const float*)d_in[8];
    float* out = (float*)d_out;

    char* ws = (char*)d_ws;
    bf16_t* xT    = (bf16_t*)(ws + XT_OFF);
    bf16_t* wg    = (bf16_t*)(ws + WG_OFF);
    bf16_t* w1b   = (bf16_t*)(ws + W1B_OFF);
    bf16_t* w2b   = (bf16_t*)(ws + W2B_OFF);
    float*  bias1 = (float*) (ws + B1_OFF);

    prep<<<260, 256, 0, stream>>>(w1, gamma, beta, mean, var, w2, w1b, w2b, bias1);
    conv1_k<<<256, 256, 0, stream>>>(guide, w1b, bias1, xT);
    conv2_k<<<2048, 256, 0, stream>>>(xT, w2b, b2, wg);
    agg_k<<<2048, 256, 0, stream>>>(wg, feature, out);
}

// Round 8
// 122.633 us; speedup vs baseline: 1.1560x; 1.0775x over previous
//
#include <hip/hip_runtime.h>

// B=4, C=256, CR=64, H=W=64, K=7, KK=49, GROUPS=16, GC=16
#define BN_EPS 1e-5f

typedef __bf16 bf16_t;
typedef __bf16 bf16x8 __attribute__((ext_vector_type(8)));
typedef __bf16 bf16x4 __attribute__((ext_vector_type(4)));
typedef __bf16 bf16x2 __attribute__((ext_vector_type(2)));
typedef float  floatx4 __attribute__((ext_vector_type(4)));

#define MFMA16(a, b, c) __builtin_amdgcn_mfma_f32_16x16x32_bf16((a), (b), (c), 0, 0, 0)

// ws layout: only xT (16384 px x 64 ch bf16 = 2 MB)
#define XT_OFF 0

// ---------------------------------------------------------------------------
// K1 conv1: one block per (b,h). BN-fold of w1 done IN-BLOCK (no prep kernel):
//   w1s[o][c] = bf16(w1[o][c] * gamma[o]*rsqrt(var[o]+eps))   (LDS, pitch 264)
//   gTs[p][c] = bf16(guide[b][c][h][p])                        (LDS transpose)
// MFMA x[64o][64p] = w1s . gTs; +bias, ReLU; store xT[bp][o] (c-contiguous).
// 256 blocks. Guide reads coalesced dwords; w1 reads coalesced float4.
// ---------------------------------------------------------------------------
#define GTP 264
#define W1P 264

__global__ __launch_bounds__(256) void conv1_k(
    const float* __restrict__ guide, const float* __restrict__ w1,
    const float* __restrict__ gamma, const float* __restrict__ beta,
    const float* __restrict__ mean,  const float* __restrict__ var,
    bf16_t* __restrict__ xT)
{
    __shared__ __attribute__((aligned(16))) bf16_t gTs[64 * GTP];  // 33.8 KB
    __shared__ __attribute__((aligned(16))) bf16_t w1s[64 * W1P];  // 33.8 KB
    const int b = blockIdx.x >> 6, h = blockIdx.x & 63;
    const int t = threadIdx.x;

    // stage w1 with BN scale folded: 16 float4 chunks per thread
#pragma unroll
    for (int i = 0; i < 16; ++i) {
        const int idx = i * 256 + t;          // 4096 chunks
        const int o = idx >> 6, cq = idx & 63;
        const float inv = gamma[o] * rsqrtf(var[o] + BN_EPS);
        const float4 v = *(const float4*)(w1 + o * 256 + cq * 4);
        bf16_t* d = &w1s[o * W1P + cq * 4];
        d[0] = (bf16_t)(v.x * inv); d[1] = (bf16_t)(v.y * inv);
        d[2] = (bf16_t)(v.z * inv); d[3] = (bf16_t)(v.w * inv);
    }
    // stage guide row transposed: coalesced dword reads (lanes = p)
    const float* gsrc = guide + (size_t)b * 256 * 4096 + h * 64;
#pragma unroll
    for (int i = 0; i < 32; ++i) {
        const int idx = i * 256 + t;
        const int c2 = idx >> 6, p = idx & 63;
        const float g0 = gsrc[(size_t)(2 * c2) * 4096 + p];
        const float g1 = gsrc[(size_t)(2 * c2 + 1) * 4096 + p];
        bf16x2 pk; pk[0] = (bf16_t)g0; pk[1] = (bf16_t)g1;
        *(bf16x2*)&gTs[p * GTP + 2 * c2] = pk;
    }
    __syncthreads();

    const int wv = t >> 6, ln = t & 63, l15 = ln & 15, q = ln >> 4;
    floatx4 acc[4] = {};
    const bf16_t* ap = &w1s[(wv * 16 + l15) * W1P];
#pragma unroll
    for (int ks = 0; ks < 8; ++ks) {
        const bf16x8 a = *(const bf16x8*)(ap + ks * 32 + q * 8);
#pragma unroll
        for (int nt = 0; nt < 4; ++nt) {
            const bf16x8 bb = *(const bf16x8*)&gTs[(nt * 16 + l15) * GTP + ks * 32 + q * 8];
            acc[nt] = MFMA16(a, bb, acc[nt]);
        }
    }
    // bias (BN) computed inline per output row
    float bi[4];
#pragma unroll
    for (int j = 0; j < 4; ++j) {
        const int o = wv * 16 + q * 4 + j;
        const float iv = gamma[o] * rsqrtf(var[o] + BN_EPS);
        bi[j] = beta[o] - mean[o] * iv;
    }
#pragma unroll
    for (int nt = 0; nt < 4; ++nt) {
        const int p = nt * 16 + l15;
        bf16x4 v;
#pragma unroll
        for (int j = 0; j < 4; ++j) v[j] = (bf16_t)fmaxf(acc[nt][j] + bi[j], 0.f);
        *(bf16x4*)(xT + ((size_t)(b * 64 + h) * 64 + p) * 64 + wv * 16 + q * 4) = v;
    }
}

// ---------------------------------------------------------------------------
// K2 conv2+agg fused: one block = (g, b, h-pair); blockIdx = (b*32+hp)*16 + g
// (XCD = g%8 -> per-XCD feat slice ~2 MB, L2-resident).
//  Parallel (no dependency, single barrier after):
//   - stage fs[16ch][8 rows][72 w] fp32, zero-padded borders (36 KB)
//   - MFMA wg[49k x 128px] = w2[g] . xT  (A-frags: fp32 w2 global -> cvt in
//     regs; B-frags: direct global xT, c-contiguous), +b2 -> wgs bf16 (13.3 KB)
//  barrier
//   - branchless agg: thread = (wq, r, cp) -> 2ch x 4w; 392 FMA from LDS;
//     residual from fs (exact fp32); coalesced float4 stores.
// LDS 49.3 KB -> 3 blocks/CU. Grid 2048.
// ---------------------------------------------------------------------------
#define FSR 72     // fs row pitch (floats): [4 pad][64 w][4 pad]
#define FSC 576    // fs channel pitch = 8*72
#define WGP 136    // wgs row pitch (bf16)

__global__ __launch_bounds__(256) void fused_k(
    const bf16_t* __restrict__ xT, const float* __restrict__ w2,
    const float* __restrict__ b2,  const float* __restrict__ feat,
    float* __restrict__ out)
{
    __shared__ __attribute__((aligned(16))) float  fs[16 * FSC];   // 36.0 KB
    __shared__ __attribute__((aligned(16))) bf16_t wgs[49 * WGP];  // 13.3 KB

    const int g = blockIdx.x & 15;
    const int rest = blockIdx.x >> 4;      // 0..127
    const int b = rest >> 5, hp = rest & 31;
    const int h0 = hp * 2;
    const int t = threadIdx.x;
    const int wv = t >> 6, ln = t & 63, l15 = ln & 15, q = ln >> 4;

    // ---- stage fs: 16 ch x 8 rows x 18 quads, zero-padded ----
#pragma unroll
    for (int i = 0; i < 9; ++i) {
        const int u = i * 256 + t;         // 2304 quads
        const int c = u / 144, rem = u - c * 144;
        const int rr = rem / 18, qq = rem - rr * 18;
        const int hh = h0 - 3 + rr;
        float4 v = {0.f, 0.f, 0.f, 0.f};
        if (qq >= 1 && qq <= 16 && hh >= 0 && hh < 64)
            v = *(const float4*)(feat + ((size_t)(b * 256 + g * 16 + c) * 64 + hh) * 64 + (qq - 1) * 4);
        *(float4*)&fs[c * FSC + rr * FSR + qq * 4] = v;
    }

    // ---- MFMA: wg[49 x 128] = w2[g] . xT ; A-frags cvt'd from fp32 in regs ----
    {
        floatx4 acc[4][2] = {};
        const bf16_t* brow = xT + ((size_t)(b * 64 + h0) * 64 + wv * 32) * 64;
#pragma unroll
        for (int ks = 0; ks < 2; ++ks) {
            bf16x8 bfr[2];
            bfr[0] = *(const bf16x8*)(brow + l15 * 64 + ks * 32 + q * 8);
            bfr[1] = *(const bf16x8*)(brow + (16 + l15) * 64 + ks * 32 + q * 8);
#pragma unroll
            for (int mt = 0; mt < 4; ++mt) {
                int row = mt * 16 + l15; if (row > 48) row = 48;  // pad rows never stored
                const float* wp = w2 + (size_t)(g * 49 + row) * 64 + ks * 32 + q * 8;
                const float4 a0 = *(const float4*)(wp);
                const float4 a1 = *(const float4*)(wp + 4);
                bf16x8 a;
                a[0] = (bf16_t)a0.x; a[1] = (bf16_t)a0.y; a[2] = (bf16_t)a0.z; a[3] = (bf16_t)a0.w;
                a[4] = (bf16_t)a1.x; a[5] = (bf16_t)a1.y; a[6] = (bf16_t)a1.z; a[7] = (bf16_t)a1.w;
                acc[mt][0] = MFMA16(a, bfr[0], acc[mt][0]);
                acc[mt][1] = MFMA16(a, bfr[1], acc[mt][1]);
            }
        }
#pragma unroll
        for (int mt = 0; mt < 4; ++mt) {
#pragma unroll
            for (int j = 0; j < 4; ++j) {
                const int k = mt * 16 + q * 4 + j;
                if (k < 49) {
                    const float bias = b2[g * 49 + k];
                    wgs[k * WGP + wv * 32 + l15]      = (bf16_t)(acc[mt][0][j] + bias);
                    wgs[k * WGP + wv * 32 + 16 + l15] = (bf16_t)(acc[mt][1][j] + bias);
                }
            }
        }
    }
    __syncthreads();

    // ---- agg: thread = (wq, r, cp) -> 2 ch x 4 w, branchless di loop ----
    const int wq = t & 15, r = (t >> 4) & 1, cp = t >> 5;   // cp in [0,8)
    const int w0 = wq * 4;
    const int ch0 = cp * 2;

    float acc[2][4] = {};
#pragma unroll
    for (int di = 0; di < 7; ++di) {
        const int ri = r + di;             // 0..7, zero-padded rows
        float f0[12], f1[12];
        {
            const float* p0 = &fs[ch0 * FSC + ri * FSR + w0];
            const float* p1 = p0 + FSC;
#pragma unroll
            for (int qj = 0; qj < 3; ++qj) {
                const floatx4 a = *(const floatx4*)(p0 + qj * 4);
                const floatx4 bq = *(const floatx4*)(p1 + qj * 4);
#pragma unroll
                for (int j = 0; j < 4; ++j) { f0[qj * 4 + j] = a[j]; f1[qj * 4 + j] = bq[j]; }
            }
        }
        const bf16_t* wrow = &wgs[(di * 7) * WGP + r * 64 + w0];
#pragma unroll
        for (int dj = 0; dj < 7; ++dj) {
            const bf16x4 wb = *(const bf16x4*)(wrow + dj * WGP);
#pragma unroll
            for (int x = 0; x < 4; ++x) {
                const float wf = (float)wb[x];
                acc[0][x] = fmaf(wf, f0[x + dj + 1], acc[0][x]);
                acc[1][x] = fmaf(wf, f1[x + dj + 1], acc[1][x]);
            }
        }
    }

    // residual from staged fp32 tile (row r+3 == h0+r), + store
#pragma unroll
    for (int c = 0; c < 2; ++c) {
        const floatx4 res = *(const floatx4*)&fs[(ch0 + c) * FSC + (r + 3) * FSR + 4 + w0];
        const size_t ob = ((size_t)(b * 256 + g * 16 + ch0 + c) * 64 + h0 + r) * 64 + w0;
        float4 o;
        o.x = acc[c][0] + res[0]; o.y = acc[c][1] + res[1];
        o.z = acc[c][2] + res[2]; o.w = acc[c][3] + res[3];
        *(float4*)(out + ob) = o;
    }
}

extern "C" void kernel_launch(void* const* d_in, const int* in_sizes, int n_in,
                              void* d_out, int out_size, void* d_ws, size_t ws_size,
                              hipStream_t stream) {
    const float* feature = (const float*)d_in[0];
    const float* guide   = (const float*)d_in[1];
    const float* w1      = (const float*)d_in[2];
    const float* gamma   = (const float*)d_in[3];
    const float* beta    = (const float*)d_in[4];
    const float* mean    = (const float*)d_in[5];
    const float* var     = (const float*)d_in[6];
    const float* w2      = (const float*)d_in[7];
    const float* b2      = (const float*)d_in[8];
    float* out = (float*)d_out;

    bf16_t* xT = (bf16_t*)((char*)d_ws + XT_OFF);

    conv1_k<<<256, 256, 0, stream>>>(guide, w1, gamma, beta, mean, var, xT);
    fused_k<<<2048, 256, 0, stream>>>(xT, w2, b2, feature, out);
}